// Round 12
// baseline (119.964 us; speedup 1.0000x reference)
//
#include <hip/hip_runtime.h>

#define NG 4096
#define RELAX 0.1875f
#define KEEPTH -5.2933049f   // logit(0.005): sigmoid(o)>0.005 <=> o>KEEPTH

__device__ __forceinline__ float linf(int i) { return -1.0f + (2.0f/63.0f)*(float)i; }
// center-first axis permutation: {7,8,6,9,5,10,4,11,3,12,2,13,1,14,0,15}
__device__ __forceinline__ int cperm(int i) { return (i & 1) ? 7 + ((i+1)>>1) : 7 - (i>>1); }

// lane-broadcast via readlane: value lands in SGPR, reused by all lanes
#define BCAST(x, s) __int_as_float(__builtin_amdgcn_readlane(__float_as_int(x), (s)))

// ---- shared device helpers (math verified r3-r11) ----
template<int T>
__device__ __forceinline__ float4 block_minmax_cs(
    const float4* __restrict__ xyz4, const float4* __restrict__ op4,
    int tid, float (*s_r)[6])
{
  float mn0=1e10f, mn1=1e10f, mn2=1e10f;
  float mx0=-1e10f, mx1=-1e10f, mx2=-1e10f;
  #pragma unroll
  for (int t = 0; t < NG/4/T; ++t) {
    const int G = t*T + tid;             // group of 4 gaussians
    float4 v0 = xyz4[3*G+0], v1 = xyz4[3*G+1], v2 = xyz4[3*G+2];
    float4 oo = op4[G];
    if (oo.x > KEEPTH) { mn0=fminf(mn0,v0.x); mx0=fmaxf(mx0,v0.x);
                         mn1=fminf(mn1,v0.y); mx1=fmaxf(mx1,v0.y);
                         mn2=fminf(mn2,v0.z); mx2=fmaxf(mx2,v0.z); }
    if (oo.y > KEEPTH) { mn0=fminf(mn0,v0.w); mx0=fmaxf(mx0,v0.w);
                         mn1=fminf(mn1,v1.x); mx1=fmaxf(mx1,v1.x);
                         mn2=fminf(mn2,v1.y); mx2=fmaxf(mx2,v1.y); }
    if (oo.z > KEEPTH) { mn0=fminf(mn0,v1.z); mx0=fmaxf(mx0,v1.z);
                         mn1=fminf(mn1,v1.w); mx1=fmaxf(mx1,v1.w);
                         mn2=fminf(mn2,v2.x); mx2=fmaxf(mx2,v2.x); }
    if (oo.w > KEEPTH) { mn0=fminf(mn0,v2.y); mx0=fmaxf(mx0,v2.y);
                         mn1=fminf(mn1,v2.z); mx1=fmaxf(mx1,v2.z);
                         mn2=fminf(mn2,v2.w); mx2=fmaxf(mx2,v2.w); }
  }
  #pragma unroll
  for (int s = 1; s < 64; s <<= 1) {
    mn0 = fminf(mn0, __shfl_xor(mn0, s)); mx0 = fmaxf(mx0, __shfl_xor(mx0, s));
    mn1 = fminf(mn1, __shfl_xor(mn1, s)); mx1 = fmaxf(mx1, __shfl_xor(mx1, s));
    mn2 = fminf(mn2, __shfl_xor(mn2, s)); mx2 = fmaxf(mx2, __shfl_xor(mx2, s));
  }
  if ((tid & 63) == 0) {
    const int w = tid >> 6;
    s_r[w][0]=mn0; s_r[w][1]=mn1; s_r[w][2]=mn2;
    s_r[w][3]=mx0; s_r[w][4]=mx1; s_r[w][5]=mx2;
  }
  __syncthreads();
  mn0 = s_r[0][0]; mn1 = s_r[0][1]; mn2 = s_r[0][2];
  mx0 = s_r[0][3]; mx1 = s_r[0][4]; mx2 = s_r[0][5];
  #pragma unroll
  for (int w = 1; w < T/64; ++w) {
    mn0 = fminf(mn0, s_r[w][0]); mn1 = fminf(mn1, s_r[w][1]); mn2 = fminf(mn2, s_r[w][2]);
    mx0 = fmaxf(mx0, s_r[w][3]); mx1 = fmaxf(mx1, s_r[w][4]); mx2 = fmaxf(mx2, s_r[w][5]);
  }
  return make_float4((mn0+mx0)*0.5f, (mn1+mx1)*0.5f, (mn2+mx2)*0.5f,
                     1.8f/fmaxf(mx0-mn0, fmaxf(mx1-mn1, mx2-mn2)));
}

__device__ __forceinline__ void transform_one(
    const float* __restrict__ xyz, const float* __restrict__ scal,
    const float* __restrict__ rot, const float* __restrict__ opac,
    int g, float cx, float cy, float cz, float sc,
    float4* __restrict__ pos, float4* __restrict__ inv)
{
  float o = opac[g];
  float sig = 1.0f/(1.0f + __expf(-o));
  float opa = (sig > 0.005f) ? sig : 0.0f;
  float xs = (xyz[3*g+0]-cx)*sc;
  float ys = (xyz[3*g+1]-cy)*sc;
  float zs = (xyz[3*g+2]-cz)*sc;
  float sdx = __expf(scal[3*g+0])*sc;
  float sdy = __expf(scal[3*g+1])*sc;
  float sdz = __expf(scal[3*g+2])*sc;
  float qr=rot[4*g+0], qx=rot[4*g+1], qy=rot[4*g+2], qz=rot[4*g+3];
  float qn = 1.0f/sqrtf(qr*qr+qx*qx+qy*qy+qz*qz);
  qr*=qn; qx*=qn; qy*=qn; qz*=qn;
  float R00 = 1.0f-2.0f*(qy*qy+qz*qz), R01 = 2.0f*(qx*qy-qr*qz), R02 = 2.0f*(qx*qz+qr*qy);
  float R10 = 2.0f*(qx*qy+qr*qz), R11 = 1.0f-2.0f*(qx*qx+qz*qz), R12 = 2.0f*(qy*qz-qr*qx);
  float R20 = 2.0f*(qx*qz-qr*qy), R21 = 2.0f*(qy*qz+qr*qx), R22 = 1.0f-2.0f*(qx*qx+qy*qy);
  float L00=R00*sdx, L01=R01*sdy, L02=R02*sdz;
  float L10=R10*sdx, L11=R11*sdy, L12=R12*sdz;
  float L20=R20*sdx, L21=R21*sdy, L22=R22*sdz;
  float a = L00*L00+L01*L01+L02*L02;
  float bb= L00*L10+L01*L11+L02*L12;
  float cc= L00*L20+L01*L21+L02*L22;
  float d = L10*L10+L11*L11+L12*L12;
  float e = L10*L20+L11*L21+L12*L22;
  float f = L20*L20+L21*L21+L22*L22;
  float det = a*d*f + 2.0f*e*cc*bb - e*e*a - cc*cc*d - bb*bb*f + 1e-24f;
  float idt = 1.0f/det;
  float ia=(d*f-e*e)*idt, ib=(e*cc-bb*f)*idt, ic=(e*bb-cc*d)*idt;
  float id=(a*f-cc*cc)*idt, ie=(bb*cc-e*a)*idt, iff=(a*d-bb*bb)*idt;
  pos[g]     = make_float4(xs, ys, zs, opa);
  inv[2*g+0] = make_float4(-0.5f*ia, -ib, -ic, -0.5f*id);
  inv[2*g+1] = make_float4(-ie, -0.5f*iff, 0.0f, 0.0f);
}

// ======================================================================
// A: prep (r10/r11-verified).  256 blocks x 512 thr.
// ======================================================================
__global__ __launch_bounds__(512) void gm_prep(
    const float* __restrict__ xyz, const float* __restrict__ scal,
    const float* __restrict__ rot, const float* __restrict__ opac,
    float4* __restrict__ pos, float4* __restrict__ inv)
{
  __shared__ float s_r[8][6];
  const int tid = threadIdx.x;
  const int b   = blockIdx.x;
  const float4* xyz4 = (const float4*)xyz;
  const float4* op4  = (const float4*)opac;
  const float4 cs = block_minmax_cs<512>(xyz4, op4, tid, s_r);
  if (tid < 16)
    transform_one(xyz, scal, rot, opac, b*16+tid, cs.x, cs.y, cs.z, cs.w, pos, inv);
}

// ======================================================================
// B: eval.  1024 blocks x 1024 thr (16 waves).  Block b owns 4 bins from
// 4 centrality strata: rank_q = q*1024 + ((b + q*331) & 1023) (bijective,
// all 64 heavy bins in stratum 0, one per block, heavy blocks first).
// Wave w scans pos[w*256..(w+1)*256) (4 coalesced prefetch-1 rounds),
// tests each gaussian against the 4 windows.  Survivors are NOT staged:
// the wave iterates the ballot mask's set bits and broadcasts the 10
// needed floats from the surviving lane's REGISTERS via readlane (SGPR,
// ~2cy) -- no LDS round-trip, no compaction, no wave barriers.  This cuts
// the serial per-record critical path ~3x (the r10/r11 bottleneck).
// 16KB LDS partials + one barrier; direct store (bijection -> no atomics).
// ======================================================================
__global__ __launch_bounds__(1024) void gm_eval(
    const float4* __restrict__ pos, const float4* __restrict__ inv,
    float* __restrict__ out)
{
  __shared__ float s_p[16][4][64];      // 16 KB per-bin partials
  const int tid  = threadIdx.x;
  const int w    = tid >> 6;            // wave 0..15
  const int lane = tid & 63;            // lane = voxel
  const int b = blockIdx.x;             // 0..1023
  const int sx = lane >> 4, sy = (lane >> 2) & 3, sz = lane & 3;

  // per-bin windows (block-uniform -> SGPR) and voxel coords (per-lane)
  float vmnx[4], vmxx[4], vmny[4], vmxy[4], vmnz[4], vmxz[4];
  float ptx[4], pty[4], ptz[4];
  #pragma unroll
  for (int q = 0; q < 4; ++q) {
    const int rank = q*1024 + ((b + q*331) & 1023);
    const int bi = cperm(rank >> 8), bj = cperm((rank >> 4) & 15), bk = cperm(rank & 15);
    vmnx[q] = linf(bi*4) - RELAX; vmxx[q] = linf(bi*4+3) + RELAX;
    vmny[q] = linf(bj*4) - RELAX; vmxy[q] = linf(bj*4+3) + RELAX;
    vmnz[q] = linf(bk*4) - RELAX; vmxz[q] = linf(bk*4+3) + RELAX;
    ptx[q] = linf(bi*4+sx); pty[q] = linf(bj*4+sy); ptz[q] = linf(bk*4+sz);
  }

  float acc[4] = {0.0f, 0.0f, 0.0f, 0.0f};
  const int gbase = w*256 + lane;
  float4 P = pos[gbase];                // prefetch round 0

  #pragma unroll
  for (int t = 0; t < 4; ++t) {
    const int g = gbase + t*64;
    float4 Pn;
    if (t < 3) Pn = pos[g + 64];        // prefetch next round
    int flags = 0;
    if (P.w > 0.0f) {
      #pragma unroll
      for (int q = 0; q < 4; ++q) {
        if (P.x > vmnx[q] && P.x < vmxx[q] &&
            P.y > vmny[q] && P.y < vmxy[q] &&
            P.z > vmnz[q] && P.z < vmxz[q]) flags |= (1 << q);
      }
    }
    float4 I0 = make_float4(0,0,0,0), I1 = make_float4(0,0,0,0);
    if (flags) { I0 = inv[2*g+0]; I1 = inv[2*g+1]; }   // survivor-only gather
    unsigned long long bm[4];
    #pragma unroll
    for (int q = 0; q < 4; ++q) bm[q] = __ballot((flags >> q) & 1);

    #pragma unroll
    for (int q = 0; q < 4; ++q) {
      unsigned long long rem = bm[q];
      while (rem) {
        const int src = (int)__builtin_ctzll(rem);
        rem &= rem - 1ull;
        const float Px = BCAST(P.x, src), Py = BCAST(P.y, src);
        const float Pz = BCAST(P.z, src), Pw = BCAST(P.w, src);
        const float a0 = BCAST(I0.x, src), a1 = BCAST(I0.y, src);
        const float a2 = BCAST(I0.z, src), a3 = BCAST(I0.w, src);
        const float a4 = BCAST(I1.x, src), a5 = BCAST(I1.y, src);
        float px = ptx[q]-Px, py = pty[q]-Py, pz = ptz[q]-Pz;
        float power = px*px*a0 + py*py*a3 + pz*pz*a5
                    + px*py*a1 + px*pz*a2 + py*pz*a4;
        power = (power > 0.0f) ? -1e10f : power;   // branchless
        acc[q] += Pw * __expf(power);
      }
    }
    P = Pn;
  }

  #pragma unroll
  for (int q = 0; q < 4; ++q) s_p[w][q][lane] = acc[q];
  __syncthreads();                      // the only block barrier
  if (w < 4) {                          // wave w stores bin w (arith recompute)
    const int rank = w*1024 + ((b + w*331) & 1023);
    const int bi = cperm(rank >> 8), bj = cperm((rank >> 4) & 15), bk = cperm(rank & 15);
    float v = 0.0f;
    #pragma unroll
    for (int u = 0; u < 16; ++u) v += s_p[u][w][lane];
    out[(bi*4+sx)*4096 + (bj*4+sy)*64 + (bk*4+sz)] = v;
  }
}

// ======================================================================
// Fallback (ws too small for 192 KB): fully fused, zero-workspace
// (r4/r6-verified).
// ======================================================================
__global__ __launch_bounds__(256) void gm_fused_nows(
    const float* __restrict__ xyz, const float* __restrict__ scal,
    const float* __restrict__ rot, const float* __restrict__ opac,
    float* __restrict__ out)
{
  __shared__ float s_r[8][6];
  __shared__ float4 s_g[256*3];
  __shared__ float  s_acc[256];
  __shared__ int    s_cnt;
  const int tid = threadIdx.x;
  const float4* xyz4 = (const float4*)xyz;
  const float4* op4  = (const float4*)opac;
  if (tid == 0) s_cnt = 0;
  const float4 cs = block_minmax_cs<256>(xyz4, op4, tid, s_r);
  const float cx = cs.x, cy = cs.y, cz = cs.z, sc = cs.w;

  const int bin = blockIdx.x;
  const int bi = bin >> 8, bj = (bin >> 4) & 15, bk = bin & 15;
  const float vminx = linf(bi*4) - RELAX, vmaxx = linf(bi*4+3) + RELAX;
  const float vminy = linf(bj*4) - RELAX, vmaxy = linf(bj*4+3) + RELAX;
  const float vminz = linf(bk*4) - RELAX, vmaxz = linf(bk*4+3) + RELAX;
  const int p    = tid & 63;
  const int part = tid >> 6;
  const int sx = p >> 4, sy = (p >> 2) & 3, sz = p & 3;
  const float ptx = linf(bi*4+sx), pty = linf(bj*4+sy), ptz = linf(bk*4+sz);
  float acc = 0.0f;
  __syncthreads();

  for (int c0 = 0; c0 < NG; c0 += 256) {
    const int g = c0 + tid;
    float o = opac[g];
    bool pass = false;
    float xs=0, ys=0, zs=0, sig=0;
    if (o > KEEPTH) {
      sig = 1.0f/(1.0f + __expf(-o));
      xs = (xyz[3*g+0]-cx)*sc;
      ys = (xyz[3*g+1]-cy)*sc;
      zs = (xyz[3*g+2]-cz)*sc;
      pass = xs > vminx && xs < vmaxx &&
             ys > vminy && ys < vmaxy &&
             zs > vminz && zs < vmaxz;
    }
    if (pass) {
      float sdx = __expf(scal[3*g+0])*sc;
      float sdy = __expf(scal[3*g+1])*sc;
      float sdz = __expf(scal[3*g+2])*sc;
      float qr=rot[4*g+0], qx=rot[4*g+1], qy=rot[4*g+2], qz=rot[4*g+3];
      float qn = 1.0f/sqrtf(qr*qr+qx*qx+qy*qy+qz*qz);
      qr*=qn; qx*=qn; qy*=qn; qz*=qn;
      float R00 = 1.0f-2.0f*(qy*qy+qz*qz), R01 = 2.0f*(qx*qy-qr*qz), R02 = 2.0f*(qx*qz+qr*qy);
      float R10 = 2.0f*(qx*qy+qr*qz), R11 = 1.0f-2.0f*(qx*qx+qz*qz), R12 = 2.0f*(qy*qz-qr*qx);
      float R20 = 2.0f*(qx*qz-qr*qy), R21 = 2.0f*(qy*qz+qr*qx), R22 = 1.0f-2.0f*(qx*qx+qy*qy);
      float L00=R00*sdx, L01=R01*sdy, L02=R02*sdz;
      float L10=R10*sdx, L11=R11*sdy, L12=R12*sdz;
      float L20=R20*sdx, L21=R21*sdy, L22=R22*sdz;
      float a = L00*L00+L01*L01+L02*L02;
      float bb= L00*L10+L01*L11+L02*L12;
      float cc= L00*L20+L01*L21+L02*L22;
      float d = L10*L10+L11*L11+L12*L12;
      float e = L10*L20+L11*L21+L12*L22;
      float f = L20*L20+L21*L21+L22*L22;
      float det = a*d*f + 2.0f*e*cc*bb - e*e*a - cc*cc*d - bb*bb*f + 1e-24f;
      float idt = 1.0f/det;
      float ia=(d*f-e*e)*idt, ib=(e*cc-bb*f)*idt, ic=(e*bb-cc*d)*idt;
      float id=(a*f-cc*cc)*idt, ie=(bb*cc-e*a)*idt, iff=(a*d-bb*bb)*idt;
      int slot = atomicAdd(&s_cnt, 1);
      s_g[3*slot+0] = make_float4(xs, ys, zs, sig);
      s_g[3*slot+1] = make_float4(-0.5f*ia, -ib, -ic, -0.5f*id);
      s_g[3*slot+2] = make_float4(-ie, -0.5f*iff, 0.0f, 0.0f);
    }
    __syncthreads();
    const int nn = s_cnt;
    #pragma unroll 4
    for (int j = part; j < nn; j += 4) {
      float4 P  = s_g[3*j+0];
      float4 I0 = s_g[3*j+1];
      float4 I1 = s_g[3*j+2];
      float px = ptx - P.x, py = pty - P.y, pz = ptz - P.z;
      float power = px*px*I0.x + py*py*I0.w + pz*pz*I1.y
                  + px*py*I0.y + px*pz*I0.z + py*pz*I1.x;
      power = (power > 0.0f) ? -1e10f : power;
      acc += P.w * __expf(power);
    }
    __syncthreads();
    if (tid == 0) s_cnt = 0;
    __syncthreads();
  }
  s_acc[tid] = acc;
  __syncthreads();
  if (tid < 64) {
    float v = s_acc[tid] + s_acc[tid+64] + s_acc[tid+128] + s_acc[tid+192];
    out[(bi*4+sx)*4096 + (bj*4+sy)*64 + (bk*4+sz)] = v;
  }
}

extern "C" void kernel_launch(void* const* d_in, const int* in_sizes, int n_in,
                              void* d_out, int out_size, void* d_ws, size_t ws_size,
                              hipStream_t stream) {
  const float* xyz  = (const float*)d_in[0];
  const float* scal = (const float*)d_in[1];
  const float* rot  = (const float*)d_in[2];
  const float* opac = (const float*)d_in[3];
  float* out = (float*)d_out;
  char* ws = (char*)d_ws;
  float4* pos = (float4*)ws;                    //  64 KB, scan-contiguous
  float4* inv = (float4*)(ws + 65536);          // 128 KB, survivor-gathered

  if (ws_size >= 196608) {
    gm_prep<<<256, 512, 0, stream>>>(xyz, scal, rot, opac, pos, inv);
    gm_eval<<<1024, 1024, 0, stream>>>(pos, inv, out);
  } else {
    gm_fused_nows<<<4096, 256, 0, stream>>>(xyz, scal, rot, opac, out);
  }
}

// Round 13
// 103.753 us; speedup vs baseline: 1.1563x; 1.1563x over previous
//
#include <hip/hip_runtime.h>

#define NG 4096
#define RELAX 0.1875f
#define KEEPTH -5.2933049f   // logit(0.005): sigmoid(o)>0.005 <=> o>KEEPTH

__device__ __forceinline__ float linf(int i) { return -1.0f + (2.0f/63.0f)*(float)i; }
// center-first axis permutation: {7,8,6,9,5,10,4,11,3,12,2,13,1,14,0,15}
__device__ __forceinline__ int cperm(int i) { return (i & 1) ? 7 + ((i+1)>>1) : 7 - (i>>1); }

// ---- shared device helpers (math verified r3-r12) ----
template<int T>
__device__ __forceinline__ float4 block_minmax_cs(
    const float4* __restrict__ xyz4, const float4* __restrict__ op4,
    int tid, float (*s_r)[6])
{
  float mn0=1e10f, mn1=1e10f, mn2=1e10f;
  float mx0=-1e10f, mx1=-1e10f, mx2=-1e10f;
  #pragma unroll
  for (int t = 0; t < NG/4/T; ++t) {
    const int G = t*T + tid;             // group of 4 gaussians
    float4 v0 = xyz4[3*G+0], v1 = xyz4[3*G+1], v2 = xyz4[3*G+2];
    float4 oo = op4[G];
    if (oo.x > KEEPTH) { mn0=fminf(mn0,v0.x); mx0=fmaxf(mx0,v0.x);
                         mn1=fminf(mn1,v0.y); mx1=fmaxf(mx1,v0.y);
                         mn2=fminf(mn2,v0.z); mx2=fmaxf(mx2,v0.z); }
    if (oo.y > KEEPTH) { mn0=fminf(mn0,v0.w); mx0=fmaxf(mx0,v0.w);
                         mn1=fminf(mn1,v1.x); mx1=fmaxf(mx1,v1.x);
                         mn2=fminf(mn2,v1.y); mx2=fmaxf(mx2,v1.y); }
    if (oo.z > KEEPTH) { mn0=fminf(mn0,v1.z); mx0=fmaxf(mx0,v1.z);
                         mn1=fminf(mn1,v1.w); mx1=fmaxf(mx1,v1.w);
                         mn2=fminf(mn2,v2.x); mx2=fmaxf(mx2,v2.x); }
    if (oo.w > KEEPTH) { mn0=fminf(mn0,v2.y); mx0=fmaxf(mx0,v2.y);
                         mn1=fminf(mn1,v2.z); mx1=fmaxf(mx1,v2.z);
                         mn2=fminf(mn2,v2.w); mx2=fmaxf(mx2,v2.w); }
  }
  #pragma unroll
  for (int s = 1; s < 64; s <<= 1) {
    mn0 = fminf(mn0, __shfl_xor(mn0, s)); mx0 = fmaxf(mx0, __shfl_xor(mx0, s));
    mn1 = fminf(mn1, __shfl_xor(mn1, s)); mx1 = fmaxf(mx1, __shfl_xor(mx1, s));
    mn2 = fminf(mn2, __shfl_xor(mn2, s)); mx2 = fmaxf(mx2, __shfl_xor(mx2, s));
  }
  if ((tid & 63) == 0) {
    const int w = tid >> 6;
    s_r[w][0]=mn0; s_r[w][1]=mn1; s_r[w][2]=mn2;
    s_r[w][3]=mx0; s_r[w][4]=mx1; s_r[w][5]=mx2;
  }
  __syncthreads();
  mn0 = s_r[0][0]; mn1 = s_r[0][1]; mn2 = s_r[0][2];
  mx0 = s_r[0][3]; mx1 = s_r[0][4]; mx2 = s_r[0][5];
  #pragma unroll
  for (int w = 1; w < T/64; ++w) {
    mn0 = fminf(mn0, s_r[w][0]); mn1 = fminf(mn1, s_r[w][1]); mn2 = fminf(mn2, s_r[w][2]);
    mx0 = fmaxf(mx0, s_r[w][3]); mx1 = fmaxf(mx1, s_r[w][4]); mx2 = fmaxf(mx2, s_r[w][5]);
  }
  return make_float4((mn0+mx0)*0.5f, (mn1+mx1)*0.5f, (mn2+mx2)*0.5f,
                     1.8f/fmaxf(mx0-mn0, fmaxf(mx1-mn1, mx2-mn2)));
}

__device__ __forceinline__ void transform_one(
    const float* __restrict__ xyz, const float* __restrict__ scal,
    const float* __restrict__ rot, const float* __restrict__ opac,
    int g, float cx, float cy, float cz, float sc,
    float4* __restrict__ pos, float4* __restrict__ inv)
{
  float o = opac[g];
  float sig = 1.0f/(1.0f + __expf(-o));
  float opa = (sig > 0.005f) ? sig : 0.0f;
  float xs = (xyz[3*g+0]-cx)*sc;
  float ys = (xyz[3*g+1]-cy)*sc;
  float zs = (xyz[3*g+2]-cz)*sc;
  float sdx = __expf(scal[3*g+0])*sc;
  float sdy = __expf(scal[3*g+1])*sc;
  float sdz = __expf(scal[3*g+2])*sc;
  float qr=rot[4*g+0], qx=rot[4*g+1], qy=rot[4*g+2], qz=rot[4*g+3];
  float qn = 1.0f/sqrtf(qr*qr+qx*qx+qy*qy+qz*qz);
  qr*=qn; qx*=qn; qy*=qn; qz*=qn;
  float R00 = 1.0f-2.0f*(qy*qy+qz*qz), R01 = 2.0f*(qx*qy-qr*qz), R02 = 2.0f*(qx*qz+qr*qy);
  float R10 = 2.0f*(qx*qy+qr*qz), R11 = 1.0f-2.0f*(qx*qx+qz*qz), R12 = 2.0f*(qy*qz-qr*qx);
  float R20 = 2.0f*(qx*qz-qr*qy), R21 = 2.0f*(qy*qz+qr*qx), R22 = 1.0f-2.0f*(qx*qx+qy*qy);
  float L00=R00*sdx, L01=R01*sdy, L02=R02*sdz;
  float L10=R10*sdx, L11=R11*sdy, L12=R12*sdz;
  float L20=R20*sdx, L21=R21*sdy, L22=R22*sdz;
  float a = L00*L00+L01*L01+L02*L02;
  float bb= L00*L10+L01*L11+L02*L12;
  float cc= L00*L20+L01*L21+L02*L22;
  float d = L10*L10+L11*L11+L12*L12;
  float e = L10*L20+L11*L21+L12*L22;
  float f = L20*L20+L21*L21+L22*L22;
  float det = a*d*f + 2.0f*e*cc*bb - e*e*a - cc*cc*d - bb*bb*f + 1e-24f;
  float idt = 1.0f/det;
  float ia=(d*f-e*e)*idt, ib=(e*cc-bb*f)*idt, ic=(e*bb-cc*d)*idt;
  float id=(a*f-cc*cc)*idt, ie=(bb*cc-e*a)*idt, iff=(a*d-bb*bb)*idt;
  pos[g]     = make_float4(xs, ys, zs, opa);
  inv[2*g+0] = make_float4(-0.5f*ia, -ib, -ic, -0.5f*id);
  inv[2*g+1] = make_float4(-ie, -0.5f*iff, 0.0f, 0.0f);
}

// ======================================================================
// A: prep (r10/r12-verified).  256 blocks x 512 thr (2 blocks/CU).
// Redundant minmax (L2-resident) + transform 16 gaussians/block into
// SoA pos[] (16B, scan-contiguous) + inv[] (32B, survivor-gathered).
// ======================================================================
__global__ __launch_bounds__(512) void gm_prep(
    const float* __restrict__ xyz, const float* __restrict__ scal,
    const float* __restrict__ rot, const float* __restrict__ opac,
    float4* __restrict__ pos, float4* __restrict__ inv)
{
  __shared__ float s_r[8][6];
  const int tid = threadIdx.x;
  const int b   = blockIdx.x;
  const float4* xyz4 = (const float4*)xyz;
  const float4* op4  = (const float4*)opac;
  const float4 cs = block_minmax_cs<512>(xyz4, op4, tid, s_r);
  if (tid < 16)
    transform_one(xyz, scal, rot, opac, b*16+tid, cs.x, cs.y, cs.z, cs.w, pos, inv);
}

// ======================================================================
// B: eval -- the r5-VERIFIED structure (<40us measured), reassembled.
// 32768 blocks x 256 thr: block = (bin, 512-gaussian slice).
// Scan the slice of SoA pos[] (2 coalesced rounds), LDS-atomic compact
// survivors (P + gathered inv), part-split eval (4 waves over records,
// lane=voxel), LDS reduce, atomicAdd merge into pre-zeroed out.
// Fine work quanta -> block-churn latency hiding + no tail (r5 evidence:
// the only eval that never appeared in top-5 dispatches).
// cperm heavy-first block order (bijection, correctness-neutral).
// ======================================================================
__global__ __launch_bounds__(256) void gm_eval(
    const float4* __restrict__ pos, const float4* __restrict__ inv,
    float* __restrict__ out)
{
  __shared__ float4 s_g[512*3];         // 24 KB (slice survivors <= 512)
  __shared__ float  s_acc[256];         //  1 KB
  __shared__ int    s_cnt;
  const int tid  = threadIdx.x;
  const int blk  = blockIdx.x;
  const int rank = blk >> 3;            // 0..4095, heavy-first
  const int sl   = blk & 7;             // slice 0..7
  const int bi = cperm(rank >> 8), bj = cperm((rank >> 4) & 15), bk = cperm(rank & 15);
  const float vminx = linf(bi*4) - RELAX, vmaxx = linf(bi*4+3) + RELAX;
  const float vminy = linf(bj*4) - RELAX, vmaxy = linf(bj*4+3) + RELAX;
  const float vminz = linf(bk*4) - RELAX, vmaxz = linf(bk*4+3) + RELAX;
  if (tid == 0) s_cnt = 0;
  __syncthreads();

  // ---- scan my 512-gaussian slice (coalesced SoA), compact survivors ----
  #pragma unroll
  for (int t = 0; t < 2; ++t) {
    const int g = sl*512 + t*256 + tid;
    float4 P = pos[g];
    if (P.w > 0.0f &&
        P.x > vminx && P.x < vmaxx &&
        P.y > vminy && P.y < vmaxy &&
        P.z > vminz && P.z < vmaxz) {
      int slot = atomicAdd(&s_cnt, 1);
      s_g[3*slot+0] = P;
      s_g[3*slot+1] = inv[2*g+0];
      s_g[3*slot+2] = inv[2*g+1];
    }
  }
  __syncthreads();
  const int n = s_cnt;
  if (n == 0) return;                   // out pre-zeroed by memset

  // ---- evaluate 64 voxels x n records (4 waves split records) ----
  const int p    = tid & 63;
  const int part = tid >> 6;            // 0..3
  const int sx = p >> 4, sy = (p >> 2) & 3, sz = p & 3;
  const float ptx = linf(bi*4+sx), pty = linf(bj*4+sy), ptz = linf(bk*4+sz);
  float acc = 0.0f;
  #pragma unroll 4
  for (int j = part; j < n; j += 4) {
    float4 P  = s_g[3*j+0];
    float4 I0 = s_g[3*j+1];
    float4 I1 = s_g[3*j+2];
    float px = ptx - P.x, py = pty - P.y, pz = ptz - P.z;
    float power = px*px*I0.x + py*py*I0.w + pz*pz*I1.y
                + px*py*I0.y + px*pz*I0.z + py*pz*I1.x;
    power = (power > 0.0f) ? -1e10f : power;   // branchless
    acc += P.w * __expf(power);
  }
  s_acc[tid] = acc;
  __syncthreads();
  if (tid < 64) {
    float v = s_acc[tid] + s_acc[tid+64] + s_acc[tid+128] + s_acc[tid+192];
    atomicAdd(&out[(bi*4+sx)*4096 + (bj*4+sy)*64 + (bk*4+sz)], v);
  }
}

// ======================================================================
// Fallback (ws too small for 192 KB): fully fused, zero-workspace
// (r4/r6-verified).
// ======================================================================
__global__ __launch_bounds__(256) void gm_fused_nows(
    const float* __restrict__ xyz, const float* __restrict__ scal,
    const float* __restrict__ rot, const float* __restrict__ opac,
    float* __restrict__ out)
{
  __shared__ float s_r[8][6];
  __shared__ float4 s_g[256*3];
  __shared__ float  s_acc[256];
  __shared__ int    s_cnt;
  const int tid = threadIdx.x;
  const float4* xyz4 = (const float4*)xyz;
  const float4* op4  = (const float4*)opac;
  if (tid == 0) s_cnt = 0;
  const float4 cs = block_minmax_cs<256>(xyz4, op4, tid, s_r);
  const float cx = cs.x, cy = cs.y, cz = cs.z, sc = cs.w;

  const int bin = blockIdx.x;
  const int bi = bin >> 8, bj = (bin >> 4) & 15, bk = bin & 15;
  const float vminx = linf(bi*4) - RELAX, vmaxx = linf(bi*4+3) + RELAX;
  const float vminy = linf(bj*4) - RELAX, vmaxy = linf(bj*4+3) + RELAX;
  const float vminz = linf(bk*4) - RELAX, vmaxz = linf(bk*4+3) + RELAX;
  const int p    = tid & 63;
  const int part = tid >> 6;
  const int sx = p >> 4, sy = (p >> 2) & 3, sz = p & 3;
  const float ptx = linf(bi*4+sx), pty = linf(bj*4+sy), ptz = linf(bk*4+sz);
  float acc = 0.0f;
  __syncthreads();

  for (int c0 = 0; c0 < NG; c0 += 256) {
    const int g = c0 + tid;
    float o = opac[g];
    bool pass = false;
    float xs=0, ys=0, zs=0, sig=0;
    if (o > KEEPTH) {
      sig = 1.0f/(1.0f + __expf(-o));
      xs = (xyz[3*g+0]-cx)*sc;
      ys = (xyz[3*g+1]-cy)*sc;
      zs = (xyz[3*g+2]-cz)*sc;
      pass = xs > vminx && xs < vmaxx &&
             ys > vminy && ys < vmaxy &&
             zs > vminz && zs < vmaxz;
    }
    if (pass) {
      float sdx = __expf(scal[3*g+0])*sc;
      float sdy = __expf(scal[3*g+1])*sc;
      float sdz = __expf(scal[3*g+2])*sc;
      float qr=rot[4*g+0], qx=rot[4*g+1], qy=rot[4*g+2], qz=rot[4*g+3];
      float qn = 1.0f/sqrtf(qr*qr+qx*qx+qy*qy+qz*qz);
      qr*=qn; qx*=qn; qy*=qn; qz*=qn;
      float R00 = 1.0f-2.0f*(qy*qy+qz*qz), R01 = 2.0f*(qx*qy-qr*qz), R02 = 2.0f*(qx*qz+qr*qy);
      float R10 = 2.0f*(qx*qy+qr*qz), R11 = 1.0f-2.0f*(qx*qx+qz*qz), R12 = 2.0f*(qy*qz-qr*qx);
      float R20 = 2.0f*(qx*qz-qr*qy), R21 = 2.0f*(qy*qz+qr*qx), R22 = 1.0f-2.0f*(qx*qx+qy*qy);
      float L00=R00*sdx, L01=R01*sdy, L02=R02*sdz;
      float L10=R10*sdx, L11=R11*sdy, L12=R12*sdz;
      float L20=R20*sdx, L21=R21*sdy, L22=R22*sdz;
      float a = L00*L00+L01*L01+L02*L02;
      float bb= L00*L10+L01*L11+L02*L12;
      float cc= L00*L20+L01*L21+L02*L22;
      float d = L10*L10+L11*L11+L12*L12;
      float e = L10*L20+L11*L21+L12*L22;
      float f = L20*L20+L21*L21+L22*L22;
      float det = a*d*f + 2.0f*e*cc*bb - e*e*a - cc*cc*d - bb*bb*f + 1e-24f;
      float idt = 1.0f/det;
      float ia=(d*f-e*e)*idt, ib=(e*cc-bb*f)*idt, ic=(e*bb-cc*d)*idt;
      float id=(a*f-cc*cc)*idt, ie=(bb*cc-e*a)*idt, iff=(a*d-bb*bb)*idt;
      int slot = atomicAdd(&s_cnt, 1);
      s_g[3*slot+0] = make_float4(xs, ys, zs, sig);
      s_g[3*slot+1] = make_float4(-0.5f*ia, -ib, -ic, -0.5f*id);
      s_g[3*slot+2] = make_float4(-ie, -0.5f*iff, 0.0f, 0.0f);
    }
    __syncthreads();
    const int nn = s_cnt;
    #pragma unroll 4
    for (int j = part; j < nn; j += 4) {
      float4 P  = s_g[3*j+0];
      float4 I0 = s_g[3*j+1];
      float4 I1 = s_g[3*j+2];
      float px = ptx - P.x, py = pty - P.y, pz = ptz - P.z;
      float power = px*px*I0.x + py*py*I0.w + pz*pz*I1.y
                  + px*py*I0.y + px*pz*I0.z + py*pz*I1.x;
      power = (power > 0.0f) ? -1e10f : power;
      acc += P.w * __expf(power);
    }
    __syncthreads();
    if (tid == 0) s_cnt = 0;
    __syncthreads();
  }
  s_acc[tid] = acc;
  __syncthreads();
  if (tid < 64) {
    float v = s_acc[tid] + s_acc[tid+64] + s_acc[tid+128] + s_acc[tid+192];
    out[(bi*4+sx)*4096 + (bj*4+sy)*64 + (bk*4+sz)] = v;
  }
}

extern "C" void kernel_launch(void* const* d_in, const int* in_sizes, int n_in,
                              void* d_out, int out_size, void* d_ws, size_t ws_size,
                              hipStream_t stream) {
  const float* xyz  = (const float*)d_in[0];
  const float* scal = (const float*)d_in[1];
  const float* rot  = (const float*)d_in[2];
  const float* opac = (const float*)d_in[3];
  float* out = (float*)d_out;
  char* ws = (char*)d_ws;
  float4* pos = (float4*)ws;                    //  64 KB, scan-contiguous
  float4* inv = (float4*)(ws + 65536);          // 128 KB, survivor-gathered

  if (ws_size >= 196608) {
    hipMemsetAsync(out, 0, out_size, stream);   // graph-capturable (r4 precedent)
    gm_prep<<<256, 512, 0, stream>>>(xyz, scal, rot, opac, pos, inv);
    gm_eval<<<4096*8, 256, 0, stream>>>(pos, inv, out);
  } else {
    gm_fused_nows<<<4096, 256, 0, stream>>>(xyz, scal, rot, opac, out);
  }
}